// Round 3
// baseline (233.564 us; speedup 1.0000x reference)
//
#include <hip/hip_runtime.h>

// out = A[j]*S + B[j],  j = floor(16*S) clamped to [0,15]
// A[j] = a[j]/Y, B[j] = (cum[j] - a[j]*j/16)/Y
// a[j] = 0.5 + 4.5*sigmoid(u[j]), Y = sum(a)/16, cum[j] = exclusive prefix(a)/16.
//
// Pure streaming op: 128 MiB in + 128 MiB out.
// R1 A/B result: plain loads -> FETCH_SIZE halved (64 MiB, LLC residency
// confirmed); plain stores -> kernel 62->80 us (write stream thrashing LLC).
// R2 (resubmit after container failure): split policy by direction:
//   loads  = plain      (keep LLC input residency across iterations)
//   stores = nontemporal (write-once stream stays out of the LLC)

typedef float vf4 __attribute__((ext_vector_type(4)));

#define MSEG 16
#define VPT  8          // float4s per thread
#define BLK  256

__global__ __launch_bounds__(BLK) void mapping_kernel(
    const vf4* __restrict__ S4,
    const float* __restrict__ u,
    vf4* __restrict__ out4,
    int n4)
{
    __shared__ float sA[MSEG];
    __shared__ float sB[MSEG];

    const int tid = threadIdx.x;

    // Lane-parallel table build in wave 0: 16 lanes compute a[i] at once,
    // log-step shfl prefix sum, write LDS. ~150 cyc + one load latency.
    if (tid < 64) {
        float a = 0.0f;
        if (tid < MSEG) {
            float sig = 1.0f / (1.0f + expf(-u[tid]));
            a = 0.5f + 4.5f * sig;
        }
        float p = a;  // inclusive prefix over lanes 0..15
        #pragma unroll
        for (int off = 1; off < MSEG; off <<= 1) {
            float t = __shfl_up(p, off, 64);
            if (tid >= off) p += t;
        }
        float total = __shfl(p, MSEG - 1, 64);  // sum of a[0..15]
        if (tid < MSEG) {
            float invY = 16.0f / total;               // Y = total/16
            float cum  = (p - a) * (1.0f / 16.0f);    // exclusive prefix /16
            sA[tid] = a * invY;
            sB[tid] = (cum - a * ((float)tid * (1.0f / 16.0f))) * invY;
        }
    }
    __syncthreads();

    // Block covers BLK*VPT consecutive float4s; thread's k-th f4 at
    // base + k*BLK -> every load/store wave-coalesced (1 KiB/instr).
    const int base = blockIdx.x * (BLK * VPT) + tid;

    if (base + (VPT - 1) * BLK < n4) {
        // Fast path: no per-element bounds checks (exact cover).
        vf4 v[VPT];
        #pragma unroll
        for (int k = 0; k < VPT; ++k)
            v[k] = S4[base + k * BLK];              // plain load: LLC residency (R1: FETCH halved)

        #pragma unroll
        for (int k = 0; k < VPT; ++k) {
            const vf4 s = v[k];
            vf4 r;
            const int jx = min(max((int)(s.x * 16.0f), 0), 15);
            const int jy = min(max((int)(s.y * 16.0f), 0), 15);
            const int jz = min(max((int)(s.z * 16.0f), 0), 15);
            const int jw = min(max((int)(s.w * 16.0f), 0), 15);
            r.x = fmaf(s.x, sA[jx], sB[jx]);
            r.y = fmaf(s.y, sA[jy], sB[jy]);
            r.z = fmaf(s.z, sA[jz], sB[jz]);
            r.w = fmaf(s.w, sA[jw], sB[jw]);
            __builtin_nontemporal_store(r, &out4[base + k * BLK]);  // NT: don't pollute LLC
        }
    } else {
        // Tail path (never taken for 32x1024x1024, kept for generality).
        #pragma unroll
        for (int k = 0; k < VPT; ++k) {
            const int i = base + k * BLK;
            if (i < n4) {
                const vf4 s = S4[i];
                vf4 r;
                const int jx = min(max((int)(s.x * 16.0f), 0), 15);
                const int jy = min(max((int)(s.y * 16.0f), 0), 15);
                const int jz = min(max((int)(s.z * 16.0f), 0), 15);
                const int jw = min(max((int)(s.w * 16.0f), 0), 15);
                r.x = fmaf(s.x, sA[jx], sB[jx]);
                r.y = fmaf(s.y, sA[jy], sB[jy]);
                r.z = fmaf(s.z, sA[jz], sB[jz]);
                r.w = fmaf(s.w, sA[jw], sB[jw]);
                __builtin_nontemporal_store(r, &out4[i]);
            }
        }
    }
}

extern "C" void kernel_launch(void* const* d_in, const int* in_sizes, int n_in,
                              void* d_out, int out_size, void* d_ws, size_t ws_size,
                              hipStream_t stream)
{
    const vf4*  S4 = (const vf4*)d_in[0];        // [32,1024,1024] fp32
    const float* u = (const float*)d_in[1];      // [16] fp32
    // d_in[2] is M == 16, hardcoded.

    vf4* out4 = (vf4*)d_out;
    const int n4 = out_size / 4;                 // 8,388,608 float4s

    const int grid = (n4 + BLK * VPT - 1) / (BLK * VPT);  // 4096
    mapping_kernel<<<grid, BLK, 0, stream>>>(S4, u, out4, n4);
}

// Round 4
// 221.538 us; speedup vs baseline: 1.0543x; 1.0543x over previous
//
#include <hip/hip_runtime.h>

// out = A[j]*S + B[j],  j = floor(16*S) clamped to [0,15]
// A[j] = a[j]/Y, B[j] = (cum[j] - a[j]*j/16)/Y
// a[j] = 0.5 + 4.5*sigmoid(u[j]), Y = sum(a)/16, cum[j] = exclusive prefix(a)/16.
//
// Policy A/B history (measured):
//   NT loads + NT stores   : ~70 us  (R0, best)
//   plain loads + * stores : ~80 us  (R1/R3; FETCH halves but LLC hit path
//                                     is no faster and allocation hurts)
// -> store policy irrelevant, NT LOADS are the winning policy. Restored here.
//
// R4 single change: VGPR_Count=28 proved the compiler re-sunk the 8 "in-flight"
// loads into 2-3-deep load->use batches (8 vf4 alone would need 32 VGPRs).
// With ~20 waves/CU x ~2.5 outstanding 1KiB loads, Little's law caps us right
// at the observed 2.5-3.7 TB/s. sched_barrier(0) between the load loop and
// the compute loop pins all 8 loads above all uses -> 8 outstanding per wave.

typedef float vf4 __attribute__((ext_vector_type(4)));

#define MSEG 16
#define VPT  8          // float4s per thread
#define BLK  256

__global__ __launch_bounds__(BLK) void mapping_kernel(
    const vf4* __restrict__ S4,
    const float* __restrict__ u,
    vf4* __restrict__ out4,
    int n4)
{
    __shared__ float sA[MSEG];
    __shared__ float sB[MSEG];

    const int tid = threadIdx.x;

    // Lane-parallel table build in wave 0: 16 lanes compute a[i] at once,
    // log-step shfl prefix sum, write LDS.
    if (tid < 64) {
        float a = 0.0f;
        if (tid < MSEG) {
            float sig = 1.0f / (1.0f + expf(-u[tid]));
            a = 0.5f + 4.5f * sig;
        }
        float p = a;  // inclusive prefix over lanes 0..15
        #pragma unroll
        for (int off = 1; off < MSEG; off <<= 1) {
            float t = __shfl_up(p, off, 64);
            if (tid >= off) p += t;
        }
        float total = __shfl(p, MSEG - 1, 64);  // sum of a[0..15]
        if (tid < MSEG) {
            float invY = 16.0f / total;               // Y = total/16
            float cum  = (p - a) * (1.0f / 16.0f);    // exclusive prefix /16
            sA[tid] = a * invY;
            sB[tid] = (cum - a * ((float)tid * (1.0f / 16.0f))) * invY;
        }
    }
    __syncthreads();

    // Block covers BLK*VPT consecutive float4s; thread's k-th f4 at
    // base + k*BLK -> every load/store wave-coalesced (1 KiB/instr).
    const int base = blockIdx.x * (BLK * VPT) + tid;

    if (base + (VPT - 1) * BLK < n4) {
        // Fast path: no per-element bounds checks (exact cover).
        vf4 v[VPT];
        #pragma unroll
        for (int k = 0; k < VPT; ++k)
            v[k] = __builtin_nontemporal_load(&S4[base + k * BLK]);

        // Pin all VPT loads above all uses: compiler may not sink loads past
        // this, so each wave keeps 8 global_load_dwordx4 outstanding
        // (waits become vmcnt(7-k) per use instead of 2-3-deep batches).
        __builtin_amdgcn_sched_barrier(0);

        #pragma unroll
        for (int k = 0; k < VPT; ++k) {
            const vf4 s = v[k];
            vf4 r;
            const int jx = min(max((int)(s.x * 16.0f), 0), 15);
            const int jy = min(max((int)(s.y * 16.0f), 0), 15);
            const int jz = min(max((int)(s.z * 16.0f), 0), 15);
            const int jw = min(max((int)(s.w * 16.0f), 0), 15);
            r.x = fmaf(s.x, sA[jx], sB[jx]);
            r.y = fmaf(s.y, sA[jy], sB[jy]);
            r.z = fmaf(s.z, sA[jz], sB[jz]);
            r.w = fmaf(s.w, sA[jw], sB[jw]);
            __builtin_nontemporal_store(r, &out4[base + k * BLK]);
        }
    } else {
        // Tail path (never taken for 32x1024x1024, kept for generality).
        #pragma unroll
        for (int k = 0; k < VPT; ++k) {
            const int i = base + k * BLK;
            if (i < n4) {
                const vf4 s = __builtin_nontemporal_load(&S4[i]);
                vf4 r;
                const int jx = min(max((int)(s.x * 16.0f), 0), 15);
                const int jy = min(max((int)(s.y * 16.0f), 0), 15);
                const int jz = min(max((int)(s.z * 16.0f), 0), 15);
                const int jw = min(max((int)(s.w * 16.0f), 0), 15);
                r.x = fmaf(s.x, sA[jx], sB[jx]);
                r.y = fmaf(s.y, sA[jy], sB[jy]);
                r.z = fmaf(s.z, sA[jz], sB[jz]);
                r.w = fmaf(s.w, sA[jw], sB[jw]);
                __builtin_nontemporal_store(r, &out4[i]);
            }
        }
    }
}

extern "C" void kernel_launch(void* const* d_in, const int* in_sizes, int n_in,
                              void* d_out, int out_size, void* d_ws, size_t ws_size,
                              hipStream_t stream)
{
    const vf4*  S4 = (const vf4*)d_in[0];        // [32,1024,1024] fp32
    const float* u = (const float*)d_in[1];      // [16] fp32
    // d_in[2] is M == 16, hardcoded.

    vf4* out4 = (vf4*)d_out;
    const int n4 = out_size / 4;                 // 8,388,608 float4s

    const int grid = (n4 + BLK * VPT - 1) / (BLK * VPT);  // 4096
    mapping_kernel<<<grid, BLK, 0, stream>>>(S4, u, out4, n4);
}